// Round 6
// baseline (771.504 us; speedup 1.0000x reference)
//
#include <hip/hip_runtime.h>

#define BATCH   1048576
#define IN_DIM  64
#define OUT_DIM 16

// ---------------------------------------------------------------------------
// Kernel 1: build At = A^T (64x16) -> ws[0:1024) and Ct = (G*A)^T (64x16)
// -> ws[1024:2048), where G = (A A^T)^-1. Gauss-Jordan w/ partial pivoting.
// Single block, 256 threads. (GJ core validated rounds 1-5.)
// ---------------------------------------------------------------------------
__global__ __launch_bounds__(256) void precompute_kernel(
    const float* __restrict__ A, float* __restrict__ ws)
{
    __shared__ float sA[16][64];
    __shared__ float M[16][32];   // [S | I]
    __shared__ float fac[16];
    __shared__ int piv;

    const int tid = threadIdx.x;

    for (int i = tid; i < 1024; i += 256) sA[i >> 6][i & 63] = A[i];
    __syncthreads();

    {
        const int i = tid >> 4, j = tid & 15;
        float s = 0.f;
        #pragma unroll
        for (int k = 0; k < 64; ++k) s = fmaf(sA[i][k], sA[j][k], s);
        M[i][j] = s;
        M[i][16 + j] = (i == j) ? 1.f : 0.f;
    }
    __syncthreads();

    for (int p = 0; p < 16; ++p) {
        if (tid == 0) {
            int best = p;
            float bv = fabsf(M[p][p]);
            for (int r = p + 1; r < 16; ++r) {
                float v = fabsf(M[r][p]);
                if (v > bv) { bv = v; best = r; }
            }
            piv = best;
        }
        __syncthreads();
        if (tid < 32) {
            const int pr = piv;
            if (pr != p) { float t = M[p][tid]; M[p][tid] = M[pr][tid]; M[pr][tid] = t; }
        }
        __syncthreads();
        const float pv = M[p][p];
        __syncthreads();
        if (tid < 32) M[p][tid] *= (1.0f / pv);
        __syncthreads();
        if (tid < 16) fac[tid] = M[tid][p];
        __syncthreads();
        for (int e = tid; e < 512; e += 256) {
            const int r = e >> 5, c = e & 31;
            if (r != p) M[r][c] = fmaf(-fac[r], M[p][c], M[r][c]);
        }
        __syncthreads();
    }

    // At[k*16 + j] = A[j][k]
    for (int e = tid; e < 1024; e += 256) {
        const int k = e >> 4, j = e & 15;
        ws[e] = sA[j][k];
    }
    // Ct[k*16 + i] = C[i][k] = sum_j G[i][j] * A[j][k]
    for (int e = tid; e < 1024; e += 256) {
        const int k = e >> 4, i = e & 15;
        float s = 0.f;
        #pragma unroll
        for (int j = 0; j < 16; ++j) s = fmaf(M[i][16 + j], sA[j][k], s);
        ws[1024 + e] = s;
    }
}

// ---------------------------------------------------------------------------
// Kernel 2: x = y - C^T (A y - b).  4 rows per thread, k-chunk streamed.
// Matrix chunks (64 contiguous floats of At/Ct) come via s_load into SGPRs
// (K$), reused across 4 rows. y is consumed chunk-wise with a one-chunk
// register double-buffer; phase 2 re-reads y from L2/L3 (deliberate,
// prefetched, independent). Live set ~106 VGPR by construction.
// ---------------------------------------------------------------------------
__global__ __launch_bounds__(256, 4) void apply_kernel(
    const float* __restrict__ y, const float* __restrict__ b,
    const float* __restrict__ ws, float* __restrict__ out)
{
    const int tid  = threadIdx.x;
    const int lane = tid & 63;
    const int wv   = tid >> 6;
    // rows handled by this thread: base + r*64, r = 0..3 (wave covers 64
    // consecutive rows per r -> coalesced)
    const size_t base = (size_t)blockIdx.x * 1024 + (size_t)wv * 256 + lane;

    const float4* __restrict__ At4 = reinterpret_cast<const float4*>(ws);
    const float4* __restrict__ Ct4 = reinterpret_cast<const float4*>(ws + 1024);
    const float4* __restrict__ y4  = reinterpret_cast<const float4*>(y);
    const float4* __restrict__ b4  = reinterpret_cast<const float4*>(b);
    float4* __restrict__ o4        = reinterpret_cast<float4*>(out);

    // t[r][j] accumulators, init to -b
    float t[4][16];
    #pragma unroll
    for (int r = 0; r < 4; ++r) {
        const size_t row = base + (size_t)r * 64;
        #pragma unroll
        for (int q = 0; q < 4; ++q) {
            const float4 bv = b4[row * 4 + q];
            t[r][4*q+0] = -bv.x; t[r][4*q+1] = -bv.y;
            t[r][4*q+2] = -bv.z; t[r][4*q+3] = -bv.w;
        }
    }

    // ---------------- phase 1: t += At^T-chunks * y-chunks ----------------
    {
        float4 cur[4];
        #pragma unroll
        for (int r = 0; r < 4; ++r) cur[r] = y4[(base + (size_t)r*64) * 16];
        #pragma unroll
        for (int kq = 0; kq < 16; ++kq) {
            float4 nxt[4];
            if (kq < 15) {
                #pragma unroll
                for (int r = 0; r < 4; ++r)
                    nxt[r] = y4[(base + (size_t)r*64) * 16 + kq + 1];
            }
            #pragma unroll
            for (int dk = 0; dk < 4; ++dk) {
                #pragma unroll
                for (int jq = 0; jq < 4; ++jq) {
                    const float4 a = At4[kq*16 + dk*4 + jq];   // uniform -> SGPR
                    #pragma unroll
                    for (int r = 0; r < 4; ++r) {
                        const float yv = (dk == 0) ? cur[r].x :
                                         (dk == 1) ? cur[r].y :
                                         (dk == 2) ? cur[r].z : cur[r].w;
                        t[r][4*jq+0] = fmaf(a.x, yv, t[r][4*jq+0]);
                        t[r][4*jq+1] = fmaf(a.y, yv, t[r][4*jq+1]);
                        t[r][4*jq+2] = fmaf(a.z, yv, t[r][4*jq+2]);
                        t[r][4*jq+3] = fmaf(a.w, yv, t[r][4*jq+3]);
                    }
                }
            }
            if (kq < 15) {
                #pragma unroll
                for (int r = 0; r < 4; ++r) cur[r] = nxt[r];
            }
        }
    }

    // ---------------- phase 2: x = y - Ct-chunks * t ----------------------
    {
        float4 cur[4];
        #pragma unroll
        for (int r = 0; r < 4; ++r) cur[r] = y4[(base + (size_t)r*64) * 16];
        #pragma unroll
        for (int kq = 0; kq < 16; ++kq) {
            float4 nxt[4];
            if (kq < 15) {
                #pragma unroll
                for (int r = 0; r < 4; ++r)
                    nxt[r] = y4[(base + (size_t)r*64) * 16 + kq + 1];
            }
            float xv[4][4];
            #pragma unroll
            for (int r = 0; r < 4; ++r) {
                xv[r][0] = cur[r].x; xv[r][1] = cur[r].y;
                xv[r][2] = cur[r].z; xv[r][3] = cur[r].w;
            }
            #pragma unroll
            for (int dk = 0; dk < 4; ++dk) {
                #pragma unroll
                for (int jq = 0; jq < 4; ++jq) {
                    const float4 c = Ct4[kq*16 + dk*4 + jq];   // uniform -> SGPR
                    #pragma unroll
                    for (int r = 0; r < 4; ++r) {
                        xv[r][dk] = fmaf(-c.x, t[r][4*jq+0], xv[r][dk]);
                        xv[r][dk] = fmaf(-c.y, t[r][4*jq+1], xv[r][dk]);
                        xv[r][dk] = fmaf(-c.z, t[r][4*jq+2], xv[r][dk]);
                        xv[r][dk] = fmaf(-c.w, t[r][4*jq+3], xv[r][dk]);
                    }
                }
            }
            #pragma unroll
            for (int r = 0; r < 4; ++r) {
                o4[(base + (size_t)r*64) * 16 + kq] =
                    make_float4(xv[r][0], xv[r][1], xv[r][2], xv[r][3]);
            }
            if (kq < 15) {
                #pragma unroll
                for (int r = 0; r < 4; ++r) cur[r] = nxt[r];
            }
        }
    }
}

// ---------------------------------------------------------------------------
extern "C" void kernel_launch(void* const* d_in, const int* in_sizes, int n_in,
                              void* d_out, int out_size, void* d_ws, size_t ws_size,
                              hipStream_t stream) {
    const float* y = (const float*)d_in[0];   // (1048576, 64)
    const float* A = (const float*)d_in[1];   // (16, 64)
    const float* b = (const float*)d_in[2];   // (1048576, 16)
    float* out = (float*)d_out;               // (1048576, 64)
    float* ws  = (float*)d_ws;                // 2048 floats: At(1024) + Ct(1024)

    precompute_kernel<<<1, 256, 0, stream>>>(A, ws);
    // 4 rows per thread: 1024 rows per 256-thread block.
    apply_kernel<<<BATCH / 1024, 256, 0, stream>>>(y, b, ws, out);
}

// Round 7
// 163.746 us; speedup vs baseline: 4.7116x; 4.7116x over previous
//
#include <hip/hip_runtime.h>

#define BATCH   1048576
#define IN_DIM  64
#define OUT_DIM 16

// ---------------------------------------------------------------------------
// Kernel 1: build At = A^T (64x16) -> ws[0:1024) and Ct = (G*A)^T (64x16)
// -> ws[1024:2048), where G = (A A^T)^-1. Gauss-Jordan w/ partial pivoting.
// Single block, 256 threads. (validated rounds 1-6)
// ---------------------------------------------------------------------------
__global__ __launch_bounds__(256) void precompute_kernel(
    const float* __restrict__ A, float* __restrict__ ws)
{
    __shared__ float sA[16][64];
    __shared__ float M[16][32];   // [S | I]
    __shared__ float fac[16];
    __shared__ int piv;

    const int tid = threadIdx.x;

    for (int i = tid; i < 1024; i += 256) sA[i >> 6][i & 63] = A[i];
    __syncthreads();

    {
        const int i = tid >> 4, j = tid & 15;
        float s = 0.f;
        #pragma unroll
        for (int k = 0; k < 64; ++k) s = fmaf(sA[i][k], sA[j][k], s);
        M[i][j] = s;
        M[i][16 + j] = (i == j) ? 1.f : 0.f;
    }
    __syncthreads();

    for (int p = 0; p < 16; ++p) {
        if (tid == 0) {
            int best = p;
            float bv = fabsf(M[p][p]);
            for (int r = p + 1; r < 16; ++r) {
                float v = fabsf(M[r][p]);
                if (v > bv) { bv = v; best = r; }
            }
            piv = best;
        }
        __syncthreads();
        if (tid < 32) {
            const int pr = piv;
            if (pr != p) { float t = M[p][tid]; M[p][tid] = M[pr][tid]; M[pr][tid] = t; }
        }
        __syncthreads();
        const float pv = M[p][p];
        __syncthreads();
        if (tid < 32) M[p][tid] *= (1.0f / pv);
        __syncthreads();
        if (tid < 16) fac[tid] = M[tid][p];
        __syncthreads();
        for (int e = tid; e < 512; e += 256) {
            const int r = e >> 5, c = e & 31;
            if (r != p) M[r][c] = fmaf(-fac[r], M[p][c], M[r][c]);
        }
        __syncthreads();
    }

    // At[k*16 + j] = A[j][k]
    for (int e = tid; e < 1024; e += 256) {
        const int k = e >> 4, j = e & 15;
        ws[e] = sA[j][k];
    }
    // Ct[k*16 + i] = C[i][k] = sum_j G[i][j] * A[j][k]
    for (int e = tid; e < 1024; e += 256) {
        const int k = e >> 4, i = e & 15;
        float s = 0.f;
        #pragma unroll
        for (int j = 0; j < 16; ++j) s = fmaf(M[i][16 + j], sA[j][k], s);
        ws[1024 + e] = s;
    }
}

// ---------------------------------------------------------------------------
// Kernel 2: x = y - C^T (A y - b), thread-per-row via wave-private swizzled
// LDS tiles. Global y/out access is fully coalesced (contiguous 1 KB per
// wave-instruction); row access happens in LDS with an XOR swizzle
// (slot = q ^ (row&15)) that achieves the 8-words/bank floor. Matrices ride
// the SMEM/K$ path (validated R4). Wave-private tiles -> no barriers.
// ---------------------------------------------------------------------------
__global__ __launch_bounds__(256, 2) void apply_kernel(
    const float* __restrict__ y, const float* __restrict__ b,
    const float* __restrict__ ws, float* __restrict__ out)
{
    __shared__ float4 yT[4][64][16];   // 64 KB: per-wave 16 KB row-tile

    const int tid = threadIdx.x;
    const int wv  = tid >> 6;          // wave id in block
    const int l   = tid & 63;          // lane
    const size_t wbase = (size_t)blockIdx.x * 256 + (size_t)wv * 64;

    const float4* __restrict__ At4  = reinterpret_cast<const float4*>(ws);        // A^T, uniform -> SGPR
    const float4* __restrict__ Ct4  = reinterpret_cast<const float4*>(ws + 1024); // C^T, uniform -> SGPR
    const float4* __restrict__ ysrc = reinterpret_cast<const float4*>(y) + wbase * 16;
    const float4* __restrict__ b4   = reinterpret_cast<const float4*>(b);
    float4* __restrict__ odst       = reinterpret_cast<float4*>(out) + wbase * 16;

    // --- stage y tile: 16 contiguous 1 KB wave-loads -> swizzled LDS ---
    #pragma unroll
    for (int i = 0; i < 16; ++i) {
        const int f   = i * 64 + l;
        const int row = f >> 4, q = f & 15;
        yT[wv][row][q ^ (row & 15)] = ysrc[f];
    }

    // --- t init from b (4 strided insts; 64 B line fully used across q) ---
    float t[16];
    #pragma unroll
    for (int q = 0; q < 4; ++q) {
        const float4 bv = b4[(wbase + l) * 4 + q];
        t[4*q+0] = -bv.x; t[4*q+1] = -bv.y; t[4*q+2] = -bv.z; t[4*q+3] = -bv.w;
    }

    // --- phase 1: t = A y - b  (row = lane, y from LDS, A^T from K$) ---
    #pragma unroll
    for (int q = 0; q < 16; ++q) {
        const float4 yv = yT[wv][l][q ^ (l & 15)];
        #pragma unroll
        for (int dk = 0; dk < 4; ++dk) {
            const float yk = (dk == 0) ? yv.x : (dk == 1) ? yv.y :
                             (dk == 2) ? yv.z : yv.w;
            const int k = q * 4 + dk;
            #pragma unroll
            for (int jq = 0; jq < 4; ++jq) {
                const float4 a = At4[k * 4 + jq];   // A[4jq..4jq+3][k]
                t[4*jq+0] = fmaf(a.x, yk, t[4*jq+0]);
                t[4*jq+1] = fmaf(a.y, yk, t[4*jq+1]);
                t[4*jq+2] = fmaf(a.z, yk, t[4*jq+2]);
                t[4*jq+3] = fmaf(a.w, yk, t[4*jq+3]);
            }
        }
    }

    // --- phase 2: x_k = y_k - sum_i C[i][k] t[i], written back in place ---
    #pragma unroll
    for (int q = 0; q < 16; ++q) {
        float4 yv = yT[wv][l][q ^ (l & 15)];
        #pragma unroll
        for (int dk = 0; dk < 4; ++dk) {
            const int k = q * 4 + dk;
            float x = (dk == 0) ? yv.x : (dk == 1) ? yv.y :
                      (dk == 2) ? yv.z : yv.w;
            #pragma unroll
            for (int iq = 0; iq < 4; ++iq) {
                const float4 c = Ct4[k * 4 + iq];   // C[4iq..4iq+3][k]
                x = fmaf(-c.x, t[4*iq+0], x);
                x = fmaf(-c.y, t[4*iq+1], x);
                x = fmaf(-c.z, t[4*iq+2], x);
                x = fmaf(-c.w, t[4*iq+3], x);
            }
            if (dk == 0) yv.x = x; else if (dk == 1) yv.y = x;
            else if (dk == 2) yv.z = x; else yv.w = x;
        }
        yT[wv][l][q ^ (l & 15)] = yv;
    }

    // --- stage out: swizzled LDS -> 16 contiguous 1 KB wave-stores ---
    #pragma unroll
    for (int i = 0; i < 16; ++i) {
        const int f   = i * 64 + l;
        const int row = f >> 4, q = f & 15;
        odst[f] = yT[wv][row][q ^ (row & 15)];
    }
}

// ---------------------------------------------------------------------------
extern "C" void kernel_launch(void* const* d_in, const int* in_sizes, int n_in,
                              void* d_out, int out_size, void* d_ws, size_t ws_size,
                              hipStream_t stream) {
    const float* y = (const float*)d_in[0];   // (1048576, 64)
    const float* A = (const float*)d_in[1];   // (16, 64)
    const float* b = (const float*)d_in[2];   // (1048576, 16)
    float* out = (float*)d_out;               // (1048576, 64)
    float* ws  = (float*)d_ws;                // 2048 floats: At(1024) + Ct(1024)

    precompute_kernel<<<1, 256, 0, stream>>>(A, ws);
    apply_kernel<<<BATCH / 256, 256, 0, stream>>>(y, b, ws, out);
}